// Round 6
// baseline (21943.304 us; speedup 1.0000x reference)
//
#include <hip/hip_runtime.h>
#include <math.h>

#define NTHR 1024

constexpr int CMAX = 8;                 // rows per MLP chunk
constexpr int L1_SIZE = 16384;          // level-1 e-buffer floats (global, per batch)

__device__ __forceinline__ int xoff(int l) { return 512 - (512 >> l); }   // l in 0..7
// LDS offsets for e levels 2..8 (floats); level l holds (256>>l) rows x 128
__device__ __forceinline__ int ldse(int l) { return 16384 - (32768 >> (l - 1)); }

// ---- one MLP chunk: eout = relu(z@W1+b1 [+lab1[u1h]])@W2+b2 --------------
// Shape: wave w (0..15) owns K-slice [16w,16w+16) in BOTH layers.
//   L1: lane owns 4 cols (float4 weight rows; 64 lanes = all 256 cols, 1 KB
//       coalesced loads, each weight read once per chunk per CU).
//   L2: lane owns 2 cols (float2 rows, 512 B coalesced).
// z / h operand reads are wave-uniform b128 broadcasts (16 FMAs per read).
// Cross-slice reduce: LDS fp32 atomicAdd into h / o (pre-init with bias+lab);
// relu is applied at L2 read time (idempotent).
template <int C>
__device__ void mlp_chunk(const float* __restrict__ z, int zstride,
                          const float* __restrict__ W1, const float* __restrict__ B1,
                          const float* __restrict__ W2, const float* __restrict__ B2,
                          const float* __restrict__ lab,   // LDS 2x256, or nullptr
                          const int*   __restrict__ u1h,   // LDS bits, or nullptr
                          int done,
                          float* __restrict__ h, float* __restrict__ o,
                          float* __restrict__ eout)
{
  const int t = threadIdx.x;
  // ---- phase 0: init h with b1 (+ folded E_lab), o with b2
  for (int idx = t; idx < 256 * C; idx += NTHR) {
    const int c2 = idx & 255, r2 = idx >> 8;
    float v = B1[c2];
    if (lab) v += lab[u1h[done + r2] * 256 + c2];
    h[idx] = v;
    (void)r2;
  }
  for (int idx = t; idx < 128 * C; idx += NTHR) o[idx] = B2[idx & 127];
  __syncthreads();
  // ---- phase 1: layer-1 partials, atomically accumulated into h
  {
    const int cq = t & 63;          // col quad -> cols 4cq..4cq+3
    const int s  = t >> 6;          // wave = K-slice, k in [16s,16s+16)
    const int c0 = 4 * cq;
    const int k0 = 16 * s;
    float4 acc[C];
#pragma unroll
    for (int r = 0; r < C; ++r) acc[r] = make_float4(0.f, 0.f, 0.f, 0.f);
#pragma unroll 1
    for (int g = 0; g < 4; ++g) {
      const int kk = k0 + 4 * g;
      const float4 w0 = *reinterpret_cast<const float4*>(W1 + (kk + 0) * 256 + c0);
      const float4 w1 = *reinterpret_cast<const float4*>(W1 + (kk + 1) * 256 + c0);
      const float4 w2 = *reinterpret_cast<const float4*>(W1 + (kk + 2) * 256 + c0);
      const float4 w3 = *reinterpret_cast<const float4*>(W1 + (kk + 3) * 256 + c0);
#pragma unroll
      for (int r = 0; r < C; ++r) {
        const float4 z4 = *reinterpret_cast<const float4*>(z + r * zstride + kk);
        acc[r].x = fmaf(z4.x, w0.x, fmaf(z4.y, w1.x, fmaf(z4.z, w2.x, fmaf(z4.w, w3.x, acc[r].x))));
        acc[r].y = fmaf(z4.x, w0.y, fmaf(z4.y, w1.y, fmaf(z4.z, w2.y, fmaf(z4.w, w3.y, acc[r].y))));
        acc[r].z = fmaf(z4.x, w0.z, fmaf(z4.y, w1.z, fmaf(z4.z, w2.z, fmaf(z4.w, w3.z, acc[r].z))));
        acc[r].w = fmaf(z4.x, w0.w, fmaf(z4.y, w1.w, fmaf(z4.z, w2.w, fmaf(z4.w, w3.w, acc[r].w))));
      }
    }
#pragma unroll
    for (int r = 0; r < C; ++r) {
      atomicAdd(&h[r * 256 + c0 + 0], acc[r].x);
      atomicAdd(&h[r * 256 + c0 + 1], acc[r].y);
      atomicAdd(&h[r * 256 + c0 + 2], acc[r].z);
      atomicAdd(&h[r * 256 + c0 + 3], acc[r].w);
    }
  }
  __syncthreads();
  // ---- phase 2: layer-2 partials (relu on the fly), accumulated into o
  {
    const int dp = t & 63;          // col pair -> cols 2dp, 2dp+1
    const int s  = t >> 6;          // K-slice, k in [16s,16s+16)
    const int d0 = 2 * dp;
    const int k0 = 16 * s;
    float2 acc[C];
#pragma unroll
    for (int r = 0; r < C; ++r) acc[r] = make_float2(0.f, 0.f);
#pragma unroll 1
    for (int g = 0; g < 4; ++g) {
      const int kk = k0 + 4 * g;
      const float2 w0 = *reinterpret_cast<const float2*>(W2 + (kk + 0) * 128 + d0);
      const float2 w1 = *reinterpret_cast<const float2*>(W2 + (kk + 1) * 128 + d0);
      const float2 w2 = *reinterpret_cast<const float2*>(W2 + (kk + 2) * 128 + d0);
      const float2 w3 = *reinterpret_cast<const float2*>(W2 + (kk + 3) * 128 + d0);
#pragma unroll
      for (int r = 0; r < C; ++r) {
        float4 h4 = *reinterpret_cast<const float4*>(h + r * 256 + kk);
        h4.x = fmaxf(h4.x, 0.f); h4.y = fmaxf(h4.y, 0.f);
        h4.z = fmaxf(h4.z, 0.f); h4.w = fmaxf(h4.w, 0.f);
        acc[r].x = fmaf(h4.x, w0.x, fmaf(h4.y, w1.x, fmaf(h4.z, w2.x, fmaf(h4.w, w3.x, acc[r].x))));
        acc[r].y = fmaf(h4.x, w0.y, fmaf(h4.y, w1.y, fmaf(h4.z, w2.y, fmaf(h4.w, w3.y, acc[r].y))));
      }
    }
#pragma unroll
    for (int r = 0; r < C; ++r) {
      atomicAdd(&o[r * 128 + d0 + 0], acc[r].x);
      atomicAdd(&o[r * 128 + d0 + 1], acc[r].y);
    }
  }
  __syncthreads();
  // ---- phase 3: copy o -> eout (LDS e-level or global level-1)
  for (int idx = t; idx < 128 * C; idx += NTHR) eout[idx] = o[idx];
  __syncthreads();
}

// ---------------- one stage; KIN folded to 256 for both stage types --------
__device__ void run_stage(const float* ein, int zstride, int rows,
                          const int* u1h,
                          const float* __restrict__ W1, const float* __restrict__ B1,
                          const float* __restrict__ W2, const float* __restrict__ B2,
                          const float* __restrict__ lab,
                          float* __restrict__ h_lds, float* __restrict__ o_lds,
                          float* __restrict__ eout)
{
  int done = 0;
  while (done < rows) {
    int c = rows - done;
    if (c > CMAX) c = CMAX;
    const float* zb = zstride ? ein + done * 256 : ein;
    float* eo = eout + done * 128;
    switch (c) {
      case 8:  mlp_chunk<8>(zb, zstride, W1, B1, W2, B2, lab, u1h, done, h_lds, o_lds, eo); break;
      case 4:  mlp_chunk<4>(zb, zstride, W1, B1, W2, B2, lab, u1h, done, h_lds, o_lds, eo); break;
      case 2:  mlp_chunk<2>(zb, zstride, W1, B1, W2, B2, lab, u1h, done, h_lds, o_lds, eo); break;
      default: mlp_chunk<1>(zb, zstride, W1, B1, W2, B2, lab, u1h, done, h_lds, o_lds, eo); break;
    }
    done += c;
  }
}

__global__ void sc_setup(const int* __restrict__ info_set,
                         const float* __restrict__ E_obs,
                         const float* __restrict__ E_lab,
                         const float* __restrict__ Wb1,
                         int* __restrict__ pos2k, float* __restrict__ lab1,
                         float* __restrict__ eroot)
{
  const int t = threadIdx.x;   // 256 threads
  pos2k[t] = -1;
  __syncthreads();
  if (t < 128) pos2k[info_set[t]] = t;
  eroot[t] = E_obs[2 * 128 + (t & 127)];
  // lab1[j][h] = sum_k E_lab[j,k] * Wb1[256+k, h]
  for (int j = 0; j < 2; ++j) {
    float s = 0.0f;
    for (int k = 0; k < 128; ++k)
      s = fmaf(E_lab[j * 128 + k], Wb1[(256 + k) * 256 + t], s);
    lab1[j * 256 + t] = s;
  }
}

__global__ __launch_bounds__(NTHR, 4)
void sc_main(const int* __restrict__ info_bits, const float* __restrict__ rin,
             const float* __restrict__ Wc1, const float* __restrict__ bc1,
             const float* __restrict__ Wc2, const float* __restrict__ bc2,
             const float* __restrict__ Wb1, const float* __restrict__ bb1,
             const float* __restrict__ Wb2, const float* __restrict__ bb2,
             const float* __restrict__ Wl, const float* __restrict__ bl,
             const int* __restrict__ pos2k, const float* __restrict__ lab1_g,
             const float* __restrict__ eroot_g,
             float* __restrict__ wsall, float* __restrict__ out)
{
  const int b = blockIdx.x;   // one block per batch element
  const int t = threadIdx.x;
  float* e1g = wsall + (size_t)b * L1_SIZE;   // level-1 e-buffer (global)

  __shared__ float e_lds[16256];          // e levels 2..8   (63.5 KB)
  __shared__ float h_lds[CMAX * 256];     //  8 KB (hidden accumulator)
  __shared__ float o_lds[CMAX * 128];     //  4 KB (output accumulator)
  __shared__ float lab_lds[512];          //  2 KB
  __shared__ float eroot[256];            //  1 KB
  __shared__ int   xh[512];               //  2 KB

  for (int idx = t; idx < 512; idx += NTHR) lab_lds[idx] = lab1_g[idx];
  if (t < 256) eroot[t] = eroot_g[t];
  __syncthreads();

  float* xO = out;
  float* fO = out + 32768;
  float* uO = out + 65536;
  float* pO = out + 98304;
  float* rO = out + 131072;

  // input pointer / stride per stage level; output per level
  auto zin = [&](int l) -> const float* {
    return (l == 0) ? eroot : (l == 1) ? e1g : e_lds + ldse(l);
  };
  auto zstr  = [&](int l) { return (l == 0) ? 0 : 256; };
  auto eoutp = [&](int l) -> float* {       // stage at level l writes level l+1
    return (l == 0) ? e1g : e_lds + ldse(l + 1);
  };

  auto do_check = [&](int l) {
    run_stage(zin(l), zstr(l), 128 >> l, nullptr,
              Wc1, bc1, Wc2, bc2, nullptr, h_lds, o_lds, eoutp(l));
  };
  auto do_bit = [&](int l) {
    run_stage(zin(l), zstr(l), 128 >> l, xh + xoff(l),
              Wb1, bb1, Wb2, bb2, lab_lds, h_lds, o_lds, eoutp(l));
  };
  auto do_leaf = [&](int i) {
    const float* e = e_lds + ldse(8);  // 1 row, 128 floats
    if (t < 64) {
      float partial = e[t] * Wl[t] + e[t + 64] * Wl[t + 64];
#pragma unroll
      for (int m = 32; m >= 1; m >>= 1) partial += __shfl_xor(partial, m);
      if (t == 0) {
        const float tv = partial + bl[0];
        const float p  = 1.0f / (1.0f + expf(-tv));
        const float rv = rin[b * 256 + i];
        const int  hd     = (rv > p) ? 1 : 0;
        const bool frozen = fabsf(p - 0.5f) > 0.25f;
        const int  k  = pos2k[i];
        const int  fc = (k >= 0) ? info_bits[b * 128 + k] : 2;
        const int  x  = (fc == 2 || frozen) ? hd : fc;
        xh[xoff(7) + (i & 1)] = x;
        pO[b * 256 + i] = p;
        uO[b * 256 + i] = (float)x;
        fO[b * 256 + i] = (k >= 0) ? 2.0f : 1.0f;
        rO[b * 256 + i] = rv;
      }
    }
    __syncthreads();
  };
  auto do_combine = [&](int l, int side) {
    const int n = 256 >> l, half = n >> 1;
    if (t < half) {
      const int u1 = xh[xoff(l) + t];
      const int u2 = xh[xoff(l) + half + t];
      if (l > 0) {
        const int base = xoff(l - 1) + side * n;
        xh[base + 2 * t]     = u1 ^ u2;
        xh[base + 2 * t + 1] = u2;
      } else {
        xO[b * 256 + 2 * t]     = (float)(u1 ^ u2);
        xO[b * 256 + 2 * t + 1] = (float)u2;
      }
    }
    __syncthreads();
  };

  // initial descent to leaf 0
  for (int l = 0; l < 8; ++l) do_check(l);
  do_leaf(0);

  for (int i = 1; i < 256; ++i) {
    const int s = __builtin_ctz(i);
    // fold completed subtrees upward; last fold lands as u1h (side 0)
    for (int j = 1; j <= s; ++j) do_combine(8 - j, (j < s) ? 1 : 0);
    const int lb = 7 - s;
    do_bit(lb);
    for (int l = lb + 1; l < 8; ++l) do_check(l);
    do_leaf(i);
  }
  // final folds; level-0 combine writes the codeword x
  for (int j = 1; j <= 8; ++j) do_combine(8 - j, 1);
}

extern "C" void kernel_launch(void* const* d_in, const int* in_sizes, int n_in,
                              void* d_out, int out_size, void* d_ws, size_t ws_size,
                              hipStream_t stream)
{
  const int*   info_bits = (const int*)  d_in[0];
  const float* rin       = (const float*)d_in[1];
  const int*   info_set  = (const int*)  d_in[2];
  const float* E_obs     = (const float*)d_in[3];
  const float* E_lab     = (const float*)d_in[4];
  const float* Wc1 = (const float*)d_in[5];
  const float* bc1 = (const float*)d_in[6];
  const float* Wc2 = (const float*)d_in[7];
  const float* bc2 = (const float*)d_in[8];
  const float* Wb1 = (const float*)d_in[9];
  const float* bb1 = (const float*)d_in[10];
  const float* Wb2 = (const float*)d_in[11];
  const float* bb2 = (const float*)d_in[12];
  const float* Wl  = (const float*)d_in[13];
  const float* bl  = (const float*)d_in[14];

  int*   pos2k = (int*)d_ws;                 // 256 ints
  float* lab1  = (float*)d_ws + 256;         // 512 floats
  float* eroot = (float*)d_ws + 768;         // 256 floats
  float* wsall = (float*)d_ws + 1024;        // 128 x 16384 floats (level-1)

  hipLaunchKernelGGL(sc_setup, dim3(1), dim3(256), 0, stream,
                     info_set, E_obs, E_lab, Wb1, pos2k, lab1, eroot);
  hipLaunchKernelGGL(sc_main, dim3(128), dim3(NTHR), 0, stream,
                     info_bits, rin,
                     Wc1, bc1, Wc2, bc2, Wb1, bb1, Wb2, bb2, Wl, bl,
                     pos2k, lab1, eroot, wsall, (float*)d_out);
}

// Round 7
// 4808.139 us; speedup vs baseline: 4.5638x; 4.5638x over previous
//
#include <hip/hip_runtime.h>
#include <math.h>

#define NTHR 1024

// per-batch global e-buffers (floats)
constexpr int E1_OFF  = 0;          // level 1: 128 rows x 128
constexpr int E2_OFF  = 16384;      // level 2: 64 rows
constexpr int E3_OFF  = 24576;      // level 3: 32 rows
constexpr int E4_OFF  = 28672;      // level 4: 16 rows
constexpr int EG_STRIDE = 30720;    // floats per batch

__device__ __forceinline__ int xoff(int l) { return 512 - (512 >> l); }   // l in 0..7
// LDS e-levels 5..8 offsets (floats): rows 8,4,2,1 (+ pad)
__device__ __forceinline__ int ldse(int l) {
  return (l == 5) ? 0 : (l == 6) ? 1024 : (l == 7) ? 1536 : 1792;
}

// ---- one MLP chunk: eout = relu(z@W1+b1 [+lab]) @ W2 + b2 ----------------
// 16 waves = 16 K-slices of 16k (both layers). L1: lane owns 4 cols (b128
// weights, zero redundancy); L2: lane owns 2 cols (b64). z/h reads are
// wave-uniform LDS broadcasts, each value read once per chunk (amp-1).
// Cross-slice reduce through red[16][8][256] with bias/lab/relu fused.
template <int C, bool ZG>
__device__ __forceinline__ void mlp_chunk(
    const float* __restrict__ zg, const float* zl, int zstr,
    const float* __restrict__ W1, const float* __restrict__ B1,
    const float* __restrict__ W2, const float* __restrict__ B2,
    const float* lab, bool uselab, const int* u1h, int done,
    float* red, float* h, float* eoutL, float* __restrict__ eoutG)
{
  const int t  = threadIdx.x;
  const int wv = t >> 6;          // K-slice 0..15  (k in [16wv,16wv+16))
  const int ln = t & 63;
  // -------- layer-1 partials --------
  {
    const int k0 = 16 * wv;
    const int c0 = 4 * ln;
    float4 acc[C];
#pragma unroll
    for (int r = 0; r < C; ++r) acc[r] = make_float4(0.f, 0.f, 0.f, 0.f);
#pragma unroll 1
    for (int g = 0; g < 8; ++g) {          // 2 k per iteration
      const int kb = k0 + 2 * g;
      const float4 w0 = *reinterpret_cast<const float4*>(W1 + (kb + 0) * 256 + c0);
      const float4 w1 = *reinterpret_cast<const float4*>(W1 + (kb + 1) * 256 + c0);
#pragma unroll
      for (int r = 0; r < C; ++r) {
        float2 z2;
        if (ZG) z2 = *reinterpret_cast<const float2*>(zg + r * zstr + kb);
        else    z2 = *reinterpret_cast<const float2*>(zl + r * zstr + kb);
        acc[r].x = fmaf(z2.x, w0.x, fmaf(z2.y, w1.x, acc[r].x));
        acc[r].y = fmaf(z2.x, w0.y, fmaf(z2.y, w1.y, acc[r].y));
        acc[r].z = fmaf(z2.x, w0.z, fmaf(z2.y, w1.z, acc[r].z));
        acc[r].w = fmaf(z2.x, w0.w, fmaf(z2.y, w1.w, acc[r].w));
      }
    }
#pragma unroll
    for (int r = 0; r < C; ++r)
      *reinterpret_cast<float4*>(red + (wv * 8 + r) * 256 + c0) = acc[r];
  }
  __syncthreads();
  // -------- layer-1 reduce + bias + lab + relu -> h --------
  if (t < 512) {
    const int r  = t >> 6;
    const int c0 = 4 * (t & 63);
    float4 s = *reinterpret_cast<const float4*>(B1 + c0);
    if (uselab) {
      const int j = u1h[done + r] & 1;
      const float4 lv = *reinterpret_cast<const float4*>(lab + j * 256 + c0);
      s.x += lv.x; s.y += lv.y; s.z += lv.z; s.w += lv.w;
    }
#pragma unroll 4
    for (int q = 0; q < 16; ++q) {
      const float4 p = *reinterpret_cast<const float4*>(red + (q * 8 + r) * 256 + c0);
      s.x += p.x; s.y += p.y; s.z += p.z; s.w += p.w;
    }
    s.x = fmaxf(s.x, 0.f); s.y = fmaxf(s.y, 0.f);
    s.z = fmaxf(s.z, 0.f); s.w = fmaxf(s.w, 0.f);
    *reinterpret_cast<float4*>(h + r * 256 + c0) = s;
  }
  __syncthreads();
  // -------- layer-2 partials --------
  {
    const int k0 = 16 * wv;
    const int c0 = 2 * ln;
    float2 acc[C];
#pragma unroll
    for (int r = 0; r < C; ++r) acc[r] = make_float2(0.f, 0.f);
#pragma unroll 1
    for (int g = 0; g < 4; ++g) {          // 4 k per iteration
      const int kb = k0 + 4 * g;
      const float2 w0 = *reinterpret_cast<const float2*>(W2 + (kb + 0) * 128 + c0);
      const float2 w1 = *reinterpret_cast<const float2*>(W2 + (kb + 1) * 128 + c0);
      const float2 w2 = *reinterpret_cast<const float2*>(W2 + (kb + 2) * 128 + c0);
      const float2 w3 = *reinterpret_cast<const float2*>(W2 + (kb + 3) * 128 + c0);
#pragma unroll
      for (int r = 0; r < C; ++r) {
        const float4 h4 = *reinterpret_cast<const float4*>(h + r * 256 + kb);
        acc[r].x = fmaf(h4.x, w0.x, fmaf(h4.y, w1.x, fmaf(h4.z, w2.x, fmaf(h4.w, w3.x, acc[r].x))));
        acc[r].y = fmaf(h4.x, w0.y, fmaf(h4.y, w1.y, fmaf(h4.z, w2.y, fmaf(h4.w, w3.y, acc[r].y))));
      }
    }
#pragma unroll
    for (int r = 0; r < C; ++r)
      *reinterpret_cast<float2*>(red + (wv * 8 + r) * 128 + c0) = acc[r];
  }
  __syncthreads();
  // -------- layer-2 reduce + bias -> eout --------
  {
    const int r = t >> 7;
    const int c = t & 127;
    if (r < C) {
      float s = B2[c];
#pragma unroll 4
      for (int q = 0; q < 16; ++q) s += red[(q * 8 + r) * 128 + c];
      if (eoutL) eoutL[r * 128 + c] = s;
      else       eoutG[r * 128 + c] = s;
    }
  }
  __syncthreads();
}

__global__ void sc_setup(const int* __restrict__ info_set,
                         const float* __restrict__ E_obs,
                         const float* __restrict__ E_lab,
                         const float* __restrict__ Wb1,
                         int* __restrict__ pos2k, float* __restrict__ lab1,
                         float* __restrict__ eroot)
{
  const int t = threadIdx.x;   // 256 threads
  pos2k[t] = -1;
  __syncthreads();
  if (t < 128) pos2k[info_set[t]] = t;
  eroot[t] = E_obs[2 * 128 + (t & 127)];
  for (int j = 0; j < 2; ++j) {
    float s = 0.0f;
    for (int k = 0; k < 128; ++k)
      s = fmaf(E_lab[j * 128 + k], Wb1[(256 + k) * 256 + t], s);
    lab1[j * 256 + t] = s;
  }
}

__global__ __launch_bounds__(NTHR, 1)
void sc_main(const int* __restrict__ info_bits, const float* __restrict__ rin,
             const float* __restrict__ Wc1, const float* __restrict__ bc1,
             const float* __restrict__ Wc2, const float* __restrict__ bc2,
             const float* __restrict__ Wb1, const float* __restrict__ bb1,
             const float* __restrict__ Wb2, const float* __restrict__ bb2,
             const float* __restrict__ Wl, const float* __restrict__ bl,
             const int* __restrict__ pos2k, const float* __restrict__ lab1_g,
             const float* __restrict__ eroot_g,
             float* __restrict__ wsall, float* __restrict__ out)
{
  const int b = blockIdx.x;
  const int t = threadIdx.x;
  float* eg = wsall + (size_t)b * EG_STRIDE;   // levels 1..4 (global)

  __shared__ float red[32768];      // 128 KB split-K partials
  __shared__ float h_lds[2048];     //   8 KB hidden
  __shared__ float e_lds[2048];     //   8 KB e-levels 5..8 (+pad)
  __shared__ float lab_lds[512];
  __shared__ float eroot[256];
  __shared__ int   xh[520];         // +8 pad (padded-row u1h reads)

  for (int idx = t; idx < 512; idx += NTHR) lab_lds[idx] = lab1_g[idx];
  if (t < 256) eroot[t] = eroot_g[t];
  if (t >= 512 && t < 520) xh[t] = 0;
  __syncthreads();

  float* xO = out;
  float* fO = out + 32768;
  float* uO = out + 65536;
  float* pO = out + 98304;
  float* rO = out + 131072;

  auto run_level = [&](int l, bool isbit) {
    const int rows = 128 >> l;
    const float* W1 = isbit ? Wb1 : Wc1;
    const float* B1 = isbit ? bb1 : bc1;
    const float* W2 = isbit ? Wb2 : Wc2;
    const float* B2 = isbit ? bb2 : bc2;
    const int* u1h = xh + xoff(l);
    // z source / eout dest per level
    const float* zg = nullptr; const float* zl = nullptr;
    int zstr = 256; bool isZG = false;
    float* eoL = nullptr; float* eoG = nullptr;
    switch (l) {
      case 0: zl = eroot; zstr = 0;            eoG = eg + E1_OFF; break;
      case 1: zg = eg + E1_OFF; isZG = true;   eoG = eg + E2_OFF; break;
      case 2: zg = eg + E2_OFF; isZG = true;   eoG = eg + E3_OFF; break;
      case 3: zg = eg + E3_OFF; isZG = true;   eoG = eg + E4_OFF; break;
      case 4: zg = eg + E4_OFF; isZG = true;   eoL = e_lds + ldse(5); break;
      case 5: zl = e_lds + ldse(5);            eoL = e_lds + ldse(6); break;
      case 6: zl = e_lds + ldse(6);            eoL = e_lds + ldse(7); break;
      default: zl = e_lds + ldse(7);           eoL = e_lds + ldse(8); break;
    }
    int done = 0;
    while (done < rows) {
      int c = rows - done;
      if (c > 8) c = 8;
      const float* zgc = zg ? zg + done * zstr : nullptr;
      const float* zlc = zl ? zl + done * zstr : nullptr;
      float* eoLc = eoL ? eoL + done * 128 : nullptr;
      float* eoGc = eoG ? eoG + done * 128 : nullptr;
      if (c == 8) {
        if (isZG) mlp_chunk<8, true >(zgc, zlc, zstr, W1, B1, W2, B2, lab_lds, isbit, u1h, done, red, h_lds, eoLc, eoGc);
        else      mlp_chunk<8, false>(zgc, zlc, zstr, W1, B1, W2, B2, lab_lds, isbit, u1h, done, red, h_lds, eoLc, eoGc);
      } else if (c == 4) {
        if (isZG) mlp_chunk<4, true >(zgc, zlc, zstr, W1, B1, W2, B2, lab_lds, isbit, u1h, done, red, h_lds, eoLc, eoGc);
        else      mlp_chunk<4, false>(zgc, zlc, zstr, W1, B1, W2, B2, lab_lds, isbit, u1h, done, red, h_lds, eoLc, eoGc);
      } else {    // c == 2 or 1 -> padded C=2
        if (isZG) mlp_chunk<2, true >(zgc, zlc, zstr, W1, B1, W2, B2, lab_lds, isbit, u1h, done, red, h_lds, eoLc, eoGc);
        else      mlp_chunk<2, false>(zgc, zlc, zstr, W1, B1, W2, B2, lab_lds, isbit, u1h, done, red, h_lds, eoLc, eoGc);
      }
      done += c;
    }
  };

  auto do_leaf = [&](int i) {
    const float* e = e_lds + ldse(8);
    if (t < 64) {
      float partial = e[t] * Wl[t] + e[t + 64] * Wl[t + 64];
#pragma unroll
      for (int m = 32; m >= 1; m >>= 1) partial += __shfl_xor(partial, m);
      if (t == 0) {
        const float tv = partial + bl[0];
        const float p  = 1.0f / (1.0f + expf(-tv));
        const float rv = rin[b * 256 + i];
        const int  hd     = (rv > p) ? 1 : 0;
        const bool frozen = fabsf(p - 0.5f) > 0.25f;
        const int  k  = pos2k[i];
        const int  fc = (k >= 0) ? info_bits[b * 128 + k] : 2;
        const int  x  = (fc == 2 || frozen) ? hd : fc;
        xh[xoff(7) + (i & 1)] = x;
        pO[b * 256 + i] = p;
        uO[b * 256 + i] = (float)x;
        fO[b * 256 + i] = (k >= 0) ? 2.0f : 1.0f;
        rO[b * 256 + i] = rv;
      }
    }
    __syncthreads();
  };
  auto do_combine = [&](int l, int side) {
    const int n = 256 >> l, half = n >> 1;
    if (t < half) {
      const int u1 = xh[xoff(l) + t];
      const int u2 = xh[xoff(l) + half + t];
      if (l > 0) {
        const int base = xoff(l - 1) + side * n;
        xh[base + 2 * t]     = u1 ^ u2;
        xh[base + 2 * t + 1] = u2;
      } else {
        xO[b * 256 + 2 * t]     = (float)(u1 ^ u2);
        xO[b * 256 + 2 * t + 1] = (float)u2;
      }
    }
    __syncthreads();
  };

  // ---- SC traversal, single stage call-site ----
  int i = 0, l = 0;
  bool isbit = false;
  while (true) {
    run_level(l, isbit);
    if (l < 7) { ++l; isbit = false; continue; }
    do_leaf(i);
    if (i == 255) break;
    ++i;
    const int s = __builtin_ctz(i);
    for (int j = 1; j <= s; ++j) do_combine(8 - j, (j < s) ? 1 : 0);
    l = 7 - s;
    isbit = true;
  }
  for (int j = 1; j <= 8; ++j) do_combine(8 - j, 1);
}

extern "C" void kernel_launch(void* const* d_in, const int* in_sizes, int n_in,
                              void* d_out, int out_size, void* d_ws, size_t ws_size,
                              hipStream_t stream)
{
  const int*   info_bits = (const int*)  d_in[0];
  const float* rin       = (const float*)d_in[1];
  const int*   info_set  = (const int*)  d_in[2];
  const float* E_obs     = (const float*)d_in[3];
  const float* E_lab     = (const float*)d_in[4];
  const float* Wc1 = (const float*)d_in[5];
  const float* bc1 = (const float*)d_in[6];
  const float* Wc2 = (const float*)d_in[7];
  const float* bc2 = (const float*)d_in[8];
  const float* Wb1 = (const float*)d_in[9];
  const float* bb1 = (const float*)d_in[10];
  const float* Wb2 = (const float*)d_in[11];
  const float* bb2 = (const float*)d_in[12];
  const float* Wl  = (const float*)d_in[13];
  const float* bl  = (const float*)d_in[14];

  int*   pos2k = (int*)d_ws;                 // 256 ints
  float* lab1  = (float*)d_ws + 256;         // 512 floats
  float* eroot = (float*)d_ws + 768;         // 256 floats
  float* wsall = (float*)d_ws + 1024;        // 128 x EG_STRIDE floats

  hipLaunchKernelGGL(sc_setup, dim3(1), dim3(256), 0, stream,
                     info_set, E_obs, E_lab, Wb1, pos2k, lab1, eroot);
  hipLaunchKernelGGL(sc_main, dim3(128), dim3(NTHR), 0, stream,
                     info_bits, rin,
                     Wc1, bc1, Wc2, bc2, Wb1, bb1, Wb2, bb2, Wl, bl,
                     pos2k, lab1, eroot, wsall, (float*)d_out);
}